// Round 12
// baseline (442.770 us; speedup 1.0000x reference)
//
#include <hip/hip_runtime.h>

#define NPTS 2048
#define NB 8
#define NC 64
#define KNN 20
#define NSLOT 16
#define NMERGE 28
#define EPS 1e-5f
#define MTOT 327680.0f  // B*N*K

// ---- workspace layout (byte offsets) ----
// stats0 f32[128] @0, stats1 f32[128] @512 (zeroed by memset)
#define WS_U_BYTE    1024        // 16384*64 f32 = 4 MB
#define WS_V_BYTE    4195328     // 16384*64 f32 = 4 MB
#define WS_IDX_BYTE  8389632     // 16384*20 i32 = 1.31 MB
#define WS_SQD_BYTE  9700352     // 16384 f64 = 128 KB   (dead after k_knn)
#define WS_SQ32_BYTE 9831424     // 16384 f32 = 64 KB    (dead after k_knn)
#define WS_HMIN_BYTE 9700352     // 16384*64 f32 = 4 MB, aliases sqd/sq32 (k_mid runs after k_knn)
// total 13894656 B

#define LDS_FENCE() asm volatile("s_waitcnt lgkmcnt(0)" ::: "memory")

__device__ __forceinline__ unsigned umax2(unsigned a, unsigned b) { return a > b ? a : b; }
__device__ __forceinline__ unsigned umin2(unsigned a, unsigned b) { return a < b ? a : b; }

// ---------------------------------------------------------------------------
// k_prep: sqd[p] = |x_p|^2 (f64) + f32 copy ; u = (W0a-W0b)@x ; v = W0b@x
// ---------------------------------------------------------------------------
__global__ __launch_bounds__(256) void k_prep(const float* __restrict__ pts,
                                              const float* __restrict__ W0,
                                              double* __restrict__ sqd,
                                              float* __restrict__ sq32,
                                              float* __restrict__ u,
                                              float* __restrict__ v) {
  const int b  = blockIdx.x >> 5;
  const int n0 = (blockIdx.x & 31) << 6;
  const int tid = threadIdx.x;
  __shared__ float WdT[64][64];
  __shared__ float WbT[64][64];
  __shared__ float xs[64][64];   // [c][p]
  for (int i = tid; i < 4096; i += 256) {
    int o = i & 63, c = i >> 6;
    float wa = W0[o * 128 + c], wb = W0[o * 128 + 64 + c];
    WdT[c][o] = wa - wb;
    WbT[c][o] = wb;
  }
  {
    int pp = tid & 63, c0 = tid >> 6;
    for (int i = 0; i < 16; i++) {
      int c = c0 + 4 * i;
      xs[c][pp] = pts[(b * 64 + c) * NPTS + n0 + pp];
    }
  }
  __syncthreads();
  if (tid < 64) {  // wave 0: f64 squared norms
    double s = 0.0;
    for (int c = 0; c < 64; c++) { double x = (double)xs[c][tid]; s += x * x; }
    sqd[b * NPTS + n0 + tid] = s;
    sq32[b * NPTS + n0 + tid] = (float)s;
  }
  const int o = tid & 63, w = tid >> 6;
  float wd[64], wb[64];
#pragma unroll
  for (int c = 0; c < 64; c++) { wd[c] = WdT[c][o]; wb[c] = WbT[c][o]; }
  for (int i = 0; i < 16; i++) {
    int p = w + 4 * i;
    float ua = 0.f, va = 0.f;
#pragma unroll
    for (int c = 0; c < 64; c++) {
      float xc = xs[c][p];
      ua += wd[c] * xc;
      va += wb[c] * xc;
    }
    int gp = b * NPTS + n0 + p;
    u[gp * 64 + o] = ua;
    v[gp * 64 + o] = va;
  }
}

// ---------------------------------------------------------------------------
// k_knn v5: 2 rows/wave (8192 waves -> 32 waves/CU of work), 256-thread
// blocks of 4 INDEPENDENT waves (no __syncthreads; per-wave LDS slices;
// in-wave LDS ordering via lgkmcnt fences). Same screen+rescore math as v4:
// per-lane top-16 u32 quantized keys over 64 candidates, row top-28 merge
// (32-lane team), exact f64 rescore, exact top-20 emit.
// ---------------------------------------------------------------------------
__global__ __launch_bounds__(256, 8) void k_knn(const float* __restrict__ pts,
                                                const double* __restrict__ sqd,
                                                const float* __restrict__ sq32,
                                                int* __restrict__ idxout) {
  const int b   = blockIdx.x >> 8;              // 256 blocks per batch
  const int tid = threadIdx.x;
  const int wv  = tid >> 6, lane = tid & 63;
  const int n0  = ((blockIdx.x & 255) << 3) + (wv << 1);  // 8 rows/block, 2/wave
  __shared__ __align__(16) float2 rows2[4][64];   // [wave][c] = x_c[n0..n0+1]
  __shared__ __align__(16) float distS[4][512];   // [wave] swizzled [2 rows][256 cols]
  const float* pb = pts + b * 64 * NPTS;
  rows2[wv][lane] = *(const float2*)(pb + lane * NPTS + n0);
  float sqr[2];
#pragma unroll
  for (int rr = 0; rr < 2; rr++) sqr[rr] = sq32[b * NPTS + n0 + rr];
  LDS_FENCE();  // rows2 visible to all lanes of this wave

  // per-lane top-16 screen, u32 keys (21-bit quantized dist | 11-bit idx)
  unsigned slot[NSLOT];
#pragma unroll
  for (int j = 0; j < NSLOT; j++) slot[j] = 0xFFFFF800u | (unsigned)j;
  unsigned wmax = 0xFFFFF800u | (NSLOT - 1);
  const int r = lane >> 5, g = lane & 31;

  for (int t = 0; t < 8; t++) {
    const int mb = t * 256;
    float facc[8];
#pragma unroll
    for (int i = 0; i < 8; i++) facc[i] = 0.f;
    const float4 sqm = *(const float4*)(sq32 + b * NPTS + mb + 4 * lane);
#pragma unroll 8
    for (int c = 0; c < 64; c++) {
      float4 xm = *(const float4*)(pb + c * NPTS + mb + 4 * lane);
      float2 xr = rows2[wv][c];  // broadcast
      facc[0] += xr.x * xm.x; facc[1] += xr.x * xm.y; facc[2] += xr.x * xm.z; facc[3] += xr.x * xm.w;
      facc[4] += xr.y * xm.x; facc[5] += xr.y * xm.y; facc[6] += xr.y * xm.z; facc[7] += xr.y * xm.w;
    }
    // swizzled store: col c=4*lane+q of row rr -> distS[wv][rr*256+(lane&1)*128+(lane>>1)*4+q]
#pragma unroll
    for (int rr = 0; rr < 2; rr++) {
      float4 dd;
      dd.x = sqr[rr] + sqm.x - 2.f * facc[rr * 4 + 0];
      dd.y = sqr[rr] + sqm.y - 2.f * facc[rr * 4 + 1];
      dd.z = sqr[rr] + sqm.z - 2.f * facc[rr * 4 + 2];
      dd.w = sqr[rr] + sqm.w - 2.f * facc[rr * 4 + 3];
      *(float4*)&distS[wv][rr * 256 + (lane & 1) * 128 + (lane >> 1) * 4] = dd;
    }
    LDS_FENCE();  // writes committed before cross-lane reads
    // reader (r,g): col mb+g*8+j4*4+q at distS[wv][r*256+j4*128+g*4+q]
#pragma unroll
    for (int j4 = 0; j4 < 2; j4++) {
      float4 dv = *(const float4*)&distS[wv][r * 256 + j4 * 128 + g * 4];
      float dq[4] = {dv.x, dv.y, dv.z, dv.w};
#pragma unroll
      for (int q = 0; q < 4; q++) {
        int m = mb + g * 8 + j4 * 4 + q;
        unsigned ub = __float_as_uint(dq[q]);
        ub ^= (ub >> 31) ? 0xFFFFFFFFu : 0x80000000u;  // monotone map
        unsigned key = (ub & 0xFFFFF800u) | (unsigned)m;
        if (key < wmax) {
#pragma unroll
          for (int j = 0; j < NSLOT; j++)
            slot[j] = (slot[j] == wmax) ? key : slot[j];
          unsigned t8[8];
#pragma unroll
          for (int j = 0; j < 8; j++) t8[j] = umax2(slot[2 * j], slot[2 * j + 1]);
          unsigned t4a = umax2(t8[0], t8[1]), t4b = umax2(t8[2], t8[3]);
          unsigned t4c = umax2(t8[4], t8[5]), t4d = umax2(t8[6], t8[7]);
          wmax = umax2(umax2(t4a, t4b), umax2(t4c, t4d));
        }
      }
    }
    LDS_FENCE();  // reads drained before next tile overwrites distS
  }

  // ---- merge: row top-28 across the 32-lane team; candidate p -> lane p
  unsigned mycand = 0xFFFFFFFFu;
  for (int p = 0; p < NMERGE; p++) {
    unsigned t8[8];
#pragma unroll
    for (int j = 0; j < 8; j++) t8[j] = umin2(slot[2 * j], slot[2 * j + 1]);
    unsigned t4a = umin2(t8[0], t8[1]), t4b = umin2(t8[2], t8[3]);
    unsigned t4c = umin2(t8[4], t8[5]), t4d = umin2(t8[6], t8[7]);
    unsigned gmin = umin2(umin2(t4a, t4b), umin2(t4c, t4d));
#pragma unroll
    for (int mk = 1; mk < 32; mk <<= 1) {
      unsigned o = __shfl_xor(gmin, mk, 32);
      gmin = umin2(gmin, o);
    }
#pragma unroll
    for (int j = 0; j < NSLOT; j++)
      if (slot[j] == gmin) slot[j] = 0xFFFFFFFFu;
    if (p == g) mycand = gmin;
  }

  // ---- exact f64 rescore of my (<=1) candidate
  const int nrow = n0 + r;
  const float* rowsF = (const float*)rows2[wv];  // rowsF[c*2+r] = x_row[c]
  unsigned long long ekey = ~0ull;
  if (mycand != 0xFFFFFFFFu) {
    const int m = (int)(mycand & 2047u);
    const float* pc = pb + m;
    double a0 = 0.0, a1 = 0.0, a2 = 0.0, a3 = 0.0;
    for (int c = 0; c < 64; c += 4) {
      a0 += (double)rowsF[(c + 0) * 2 + r] * (double)pc[(c + 0) * NPTS];
      a1 += (double)rowsF[(c + 1) * 2 + r] * (double)pc[(c + 1) * NPTS];
      a2 += (double)rowsF[(c + 2) * 2 + r] * (double)pc[(c + 2) * NPTS];
      a3 += (double)rowsF[(c + 3) * 2 + r] * (double)pc[(c + 3) * NPTS];
    }
    double d = sqd[b * NPTS + nrow] + sqd[b * NPTS + m] - 2.0 * ((a0 + a1) + (a2 + a3));
    unsigned long long ub = (unsigned long long)__double_as_longlong(d);
    ub ^= (ub >> 63) ? 0xFFFFFFFFFFFFFFFFull : 0x8000000000000000ull;
    ekey = (ub & ~2047ull) | (unsigned long long)(unsigned)m;
  }

  // ---- exact top-20, ascending (matches lax.top_k incl. index tie-break)
  const int row = b * NPTS + nrow;
  for (int p = 0; p < KNN; p++) {
    unsigned long long lmin = ekey;
#pragma unroll
    for (int mk = 1; mk < 32; mk <<= 1) {
      unsigned long long o = __shfl_xor(lmin, mk, 32);
      lmin = o < lmin ? o : lmin;
    }
    if (g == 0) idxout[row * KNN + p] = (int)(lmin & 2047ull);
    if (ekey == lmin) ekey = ~0ull;
  }
}

// ---------------------------------------------------------------------------
// k_stats0: sum/sumsq per channel of h0 = u[row] + v[idx]
// ---------------------------------------------------------------------------
__global__ __launch_bounds__(256) void k_stats0(const float* __restrict__ u,
                                                const float* __restrict__ v,
                                                const int* __restrict__ idx,
                                                float* __restrict__ stats) {
  const int tid = threadIdx.x, o = tid & 63, w = tid >> 6;
  float s1 = 0.f, s2 = 0.f;
  const int r0 = blockIdx.x * 64;
  for (int i = 0; i < 16; i++) {
    int row = r0 + w + 4 * i;
    int b = row >> 11;
    float uo = u[row * 64 + o];
    const int* ip = idx + row * KNN;
    for (int k = 0; k < KNN; k++) {
      int j = ip[k];
      float h = uo + v[(b * NPTS + j) * 64 + o];
      s1 += h; s2 += h * h;
    }
  }
  __shared__ float red[2][256];
  red[0][tid] = s1; red[1][tid] = s2;
  __syncthreads();
  if (tid < 64) {
    float a  = red[0][tid] + red[0][tid + 64] + red[0][tid + 128] + red[0][tid + 192];
    float bb = red[1][tid] + red[1][tid + 64] + red[1][tid + 128] + red[1][tid + 192];
    atomicAdd(&stats[o], a);
    atomicAdd(&stats[64 + o], bb);
  }
}

// ---------------------------------------------------------------------------
// k_mid: h0n = relu(a0*(u+v)+c0); h1 = W1 @ h0n; accumulate BN1 stats;
// store per-row max/min of h1 (max-over-K commutes with BN1 affine + relu).
// ---------------------------------------------------------------------------
__global__ __launch_bounds__(256) void k_mid(const float* __restrict__ u,
                                             const float* __restrict__ v,
                                             const int* __restrict__ idx,
                                             const float* __restrict__ W1,
                                             const float* __restrict__ g0,
                                             const float* __restrict__ b0,
                                             const float* __restrict__ stats0,
                                             float* __restrict__ stats1,
                                             float* __restrict__ hmax,
                                             float* __restrict__ hmin) {
  const int tid = threadIdx.x, o = tid & 63, w = tid >> 6;
  __shared__ float W1s[64][65];
  __shared__ float hbuf[4][4][64];
  for (int i = tid; i < 4096; i += 256) W1s[i >> 6][i & 63] = W1[i];
  __syncthreads();
  float mean = stats0[o] / MTOT;
  float var  = stats0[64 + o] / MTOT - mean * mean;
  float a0 = g0[o] * rsqrtf(var + EPS);
  float c0 = b0[o] - mean * a0;
  float w1r[64];
#pragma unroll
  for (int c = 0; c < 64; c++) w1r[c] = W1s[o][c];
  float s1 = 0.f, s2 = 0.f;
  const int r0 = blockIdx.x * 16 + w * 4;
  for (int rr = 0; rr < 4; rr++) {
    const int row = r0 + rr;
    const int b = row >> 11, n = row & 2047;
    const float uo = u[row * 64 + o];
    const int* ip = idx + row * KNN;
    float hmx = -1e30f, hmn = 1e30f;
    for (int kb = 0; kb < 5; kb++) {
#pragma unroll
      for (int kk = 0; kk < 4; kk++) {
        int j = ip[kb * 4 + kk];
        float h0 = uo + v[(b * NPTS + j) * 64 + o];
        hbuf[w][kk][o] = fmaxf(a0 * h0 + c0, 0.f);
      }
      __syncthreads();
#pragma unroll
      for (int kk = 0; kk < 4; kk++) {
        float h1 = 0.f;
#pragma unroll
        for (int c4 = 0; c4 < 16; c4++) {
          float4 hh = *(const float4*)&hbuf[w][kk][c4 * 4];
          h1 += w1r[c4 * 4 + 0] * hh.x + w1r[c4 * 4 + 1] * hh.y +
                w1r[c4 * 4 + 2] * hh.z + w1r[c4 * 4 + 3] * hh.w;
        }
        s1 += h1; s2 += h1 * h1;
        hmx = fmaxf(hmx, h1); hmn = fminf(hmn, h1);
      }
      __syncthreads();
    }
    hmax[(b * 64 + o) * NPTS + n] = hmx;
    hmin[(b * 64 + o) * NPTS + n] = hmn;
  }
  __shared__ float red[2][256];
  red[0][tid] = s1; red[1][tid] = s2;
  __syncthreads();
  if (tid < 64) {
    float a  = red[0][tid] + red[0][tid + 64] + red[0][tid + 128] + red[0][tid + 192];
    float bb = red[1][tid] + red[1][tid + 64] + red[1][tid + 128] + red[1][tid + 192];
    atomicAdd(&stats1[o], a);
    atomicAdd(&stats1[64 + o], bb);
  }
}

// ---------------------------------------------------------------------------
// k_final: out = relu(a1*(a1>=0 ? hmax : hmin) + c1)
// ---------------------------------------------------------------------------
__global__ __launch_bounds__(256) void k_final(const float* __restrict__ hmaxO,
                                               const float* __restrict__ hmin,
                                               const float* __restrict__ stats1,
                                               const float* __restrict__ g1,
                                               const float* __restrict__ b1,
                                               float* __restrict__ out) {
  const int i = blockIdx.x * 256 + threadIdx.x;
  const int o = (i >> 11) & 63;
  float mean = stats1[o] / MTOT;
  float var  = stats1[64 + o] / MTOT - mean * mean;
  float a1 = g1[o] * rsqrtf(var + EPS);
  float c1 = b1[o] - mean * a1;
  float pick = (a1 >= 0.f) ? hmaxO[i] : hmin[i];
  out[i] = fmaxf(a1 * pick + c1, 0.f);
}

extern "C" void kernel_launch(void* const* d_in, const int* in_sizes, int n_in,
                              void* d_out, int out_size, void* d_ws, size_t ws_size,
                              hipStream_t stream) {
  const float* pts = (const float*)d_in[0];
  const float* W0  = (const float*)d_in[1];
  const float* g0  = (const float*)d_in[2];
  const float* b0  = (const float*)d_in[3];
  const float* W1  = (const float*)d_in[4];
  const float* g1  = (const float*)d_in[5];
  const float* b1  = (const float*)d_in[6];
  float* out = (float*)d_out;
  float* ws  = (float*)d_ws;

  float*  stats0 = ws;
  float*  stats1 = ws + 128;
  float*  u      = (float*)((char*)d_ws + WS_U_BYTE);
  float*  v      = (float*)((char*)d_ws + WS_V_BYTE);
  int*    idx    = (int*)((char*)d_ws + WS_IDX_BYTE);
  double* sqd    = (double*)((char*)d_ws + WS_SQD_BYTE);   // dead after k_knn
  float*  sq32   = (float*)((char*)d_ws + WS_SQ32_BYTE);   // dead after k_knn
  float*  hmin   = (float*)((char*)d_ws + WS_HMIN_BYTE);   // aliases sqd/sq32 (ok)
  // hmax aliases d_out (k_final rewrites it in place)

  hipMemsetAsync(d_ws, 0, 1024, stream);  // zero stats
  k_prep  <<<256,  256, 0, stream>>>(pts, W0, sqd, sq32, u, v);
  k_knn   <<<2048, 256, 0, stream>>>(pts, sqd, sq32, idx);
  k_stats0<<<256,  256, 0, stream>>>(u, v, idx, stats0);
  k_mid   <<<1024, 256, 0, stream>>>(u, v, idx, W1, g0, b0, stats0, stats1, out, hmin);
  k_final <<<4096, 256, 0, stream>>>(out, hmin, stats1, g1, b1, out);
}

// Round 13
// 373.457 us; speedup vs baseline: 1.1856x; 1.1856x over previous
//
#include <hip/hip_runtime.h>

#define NPTS 2048
#define NB 8
#define NC 64
#define KNN 20
#define NSLOT 16
#define NMERGE 28
#define NCOPY 8
#define EPS 1e-5f
#define MTOT 327680.0f  // B*N*K

// ---- workspace layout (byte offsets) ----
// stats0c f32[8][128] @0 (split-atomic copies), stats1 f32[128] @4096 (memset 4608)
#define WS_U_BYTE    5120        // 16384*64 f32 = 4 MB
#define WS_V_BYTE    4199424     // 16384*64 f32 = 4 MB
#define WS_IDX_BYTE  8393728     // 16384*20 i32 = 1.31 MB
#define WS_SQD_BYTE  9704448     // 16384 f64 = 128 KB   (dead after k_knn)
#define WS_SQ32_BYTE 9835520     // 16384 f32 = 64 KB    (dead after k_knn)
#define WS_HMIN_BYTE 9704448     // 16384*64 f32 = 4 MB, aliases sqd/sq32 (k_mid after k_knn)
// total 13898752 B

#define LDS_FENCE() asm volatile("s_waitcnt lgkmcnt(0)" ::: "memory")

__device__ __forceinline__ unsigned umax2(unsigned a, unsigned b) { return a > b ? a : b; }
__device__ __forceinline__ unsigned umin2(unsigned a, unsigned b) { return a < b ? a : b; }

// ---------------------------------------------------------------------------
// k_prep: sqd[p] = |x_p|^2 (f64) + f32 copy ; u = (W0a-W0b)@x ; v = W0b@x
// ---------------------------------------------------------------------------
__global__ __launch_bounds__(256) void k_prep(const float* __restrict__ pts,
                                              const float* __restrict__ W0,
                                              double* __restrict__ sqd,
                                              float* __restrict__ sq32,
                                              float* __restrict__ u,
                                              float* __restrict__ v) {
  const int b  = blockIdx.x >> 5;
  const int n0 = (blockIdx.x & 31) << 6;
  const int tid = threadIdx.x;
  __shared__ float WdT[64][64];
  __shared__ float WbT[64][64];
  __shared__ float xs[64][64];   // [c][p]
  for (int i = tid; i < 4096; i += 256) {
    int o = i & 63, c = i >> 6;
    float wa = W0[o * 128 + c], wb = W0[o * 128 + 64 + c];
    WdT[c][o] = wa - wb;
    WbT[c][o] = wb;
  }
  {
    int pp = tid & 63, c0 = tid >> 6;
    for (int i = 0; i < 16; i++) {
      int c = c0 + 4 * i;
      xs[c][pp] = pts[(b * 64 + c) * NPTS + n0 + pp];
    }
  }
  __syncthreads();
  if (tid < 64) {  // wave 0: f64 squared norms
    double s = 0.0;
    for (int c = 0; c < 64; c++) { double x = (double)xs[c][tid]; s += x * x; }
    sqd[b * NPTS + n0 + tid] = s;
    sq32[b * NPTS + n0 + tid] = (float)s;
  }
  const int o = tid & 63, w = tid >> 6;
  float wd[64], wb[64];
#pragma unroll
  for (int c = 0; c < 64; c++) { wd[c] = WdT[c][o]; wb[c] = WbT[c][o]; }
  for (int i = 0; i < 16; i++) {
    int p = w + 4 * i;
    float ua = 0.f, va = 0.f;
#pragma unroll
    for (int c = 0; c < 64; c++) {
      float xc = xs[c][p];
      ua += wd[c] * xc;
      va += wb[c] * xc;
    }
    int gp = b * NPTS + n0 + p;
    u[gp * 64 + o] = ua;
    v[gp * 64 + o] = va;
  }
}

// ---------------------------------------------------------------------------
// k_knn v6: v4 core (212 us measured: 4096 x 64, 4 rows/wave, per-lane top-16
// u32 quantized keys, balanced trees, row top-28 merge, exact f64 rescore,
// exact top-20) + fused BN0-stats epilogue: winners stashed in LDS during
// emit, lane=channel accumulates sum/sumsq of h0 = u[row]+v[idx], split
// atomics over NCOPY copies (contention 4096 -> 512 adds/address).
// ---------------------------------------------------------------------------
__global__ __launch_bounds__(64) void k_knn(const float* __restrict__ pts,
                                            const double* __restrict__ sqd,
                                            const float* __restrict__ sq32,
                                            const float* __restrict__ u,
                                            const float* __restrict__ v,
                                            int* __restrict__ idxout,
                                            float* __restrict__ stats0c) {
  const int b  = blockIdx.x >> 9;           // 512 blocks per batch
  const int n0 = (blockIdx.x & 511) << 2;   // 4 rows
  const int lane = threadIdx.x;
  __shared__ __align__(16) float4 rows4[64];     // [c] = x[n0..n0+3]
  __shared__ __align__(16) float distS[1024];    // swizzled [4 rows][256 cols]
  __shared__ int widxS[4][KNN];                  // emitted winners per row
  const float* pb = pts + b * 64 * NPTS;
  rows4[lane] = *(const float4*)(pb + lane * NPTS + n0);
  float sqr[4];
#pragma unroll
  for (int rr = 0; rr < 4; rr++) sqr[rr] = sq32[b * NPTS + n0 + rr];
  __syncthreads();

  unsigned slot[NSLOT];
#pragma unroll
  for (int j = 0; j < NSLOT; j++) slot[j] = 0xFFFFF800u | (unsigned)j;
  unsigned wmax = 0xFFFFF800u | (NSLOT - 1);
  const int r = lane >> 4, g = lane & 15;

  for (int t = 0; t < 8; t++) {
    const int mb = t * 256;
    float facc[16];
#pragma unroll
    for (int i = 0; i < 16; i++) facc[i] = 0.f;
    const float4 sqm = *(const float4*)(sq32 + b * NPTS + mb + 4 * lane);
#pragma unroll 8
    for (int c = 0; c < 64; c++) {
      float4 xm = *(const float4*)(pb + c * NPTS + mb + 4 * lane);
      float4 xr = rows4[c];  // broadcast
      facc[0]  += xr.x * xm.x; facc[1]  += xr.x * xm.y; facc[2]  += xr.x * xm.z; facc[3]  += xr.x * xm.w;
      facc[4]  += xr.y * xm.x; facc[5]  += xr.y * xm.y; facc[6]  += xr.y * xm.z; facc[7]  += xr.y * xm.w;
      facc[8]  += xr.z * xm.x; facc[9]  += xr.z * xm.y; facc[10] += xr.z * xm.z; facc[11] += xr.z * xm.w;
      facc[12] += xr.w * xm.x; facc[13] += xr.w * xm.y; facc[14] += xr.w * xm.z; facc[15] += xr.w * xm.w;
    }
    // swizzled store: col 4*lane+q of row rr -> distS[rr*256+(lane&3)*64+(lane>>2)*4+q]
#pragma unroll
    for (int rr = 0; rr < 4; rr++) {
      float4 dd;
      dd.x = sqr[rr] + sqm.x - 2.f * facc[rr * 4 + 0];
      dd.y = sqr[rr] + sqm.y - 2.f * facc[rr * 4 + 1];
      dd.z = sqr[rr] + sqm.z - 2.f * facc[rr * 4 + 2];
      dd.w = sqr[rr] + sqm.w - 2.f * facc[rr * 4 + 3];
      *(float4*)&distS[rr * 256 + (lane & 3) * 64 + (lane >> 2) * 4] = dd;
    }
    __syncthreads();
    // reader (r,g): col mb+g*16+j4*4+q at distS[r*256+j4*64+g*4+q]
#pragma unroll
    for (int j4 = 0; j4 < 4; j4++) {
      float4 dv = *(const float4*)&distS[r * 256 + j4 * 64 + g * 4];
      float dq[4] = {dv.x, dv.y, dv.z, dv.w};
#pragma unroll
      for (int q = 0; q < 4; q++) {
        int m = mb + g * 16 + j4 * 4 + q;
        unsigned ub = __float_as_uint(dq[q]);
        ub ^= (ub >> 31) ? 0xFFFFFFFFu : 0x80000000u;  // monotone map
        unsigned key = (ub & 0xFFFFF800u) | (unsigned)m;
        if (key < wmax) {
#pragma unroll
          for (int j = 0; j < NSLOT; j++)
            slot[j] = (slot[j] == wmax) ? key : slot[j];
          unsigned t8[8];
#pragma unroll
          for (int j = 0; j < 8; j++) t8[j] = umax2(slot[2 * j], slot[2 * j + 1]);
          unsigned t4a = umax2(t8[0], t8[1]), t4b = umax2(t8[2], t8[3]);
          unsigned t4c = umax2(t8[4], t8[5]), t4d = umax2(t8[6], t8[7]);
          wmax = umax2(umax2(t4a, t4b), umax2(t4c, t4d));
        }
      }
    }
    __syncthreads();  // WAR before next tile rewrites distS
  }

  // ---- merge: row top-28 across 16 lanes; candidate p -> lane (p&15), pos (p>>4)
  unsigned mycand[2] = {0xFFFFFFFFu, 0xFFFFFFFFu};
  for (int p = 0; p < NMERGE; p++) {
    unsigned t8[8];
#pragma unroll
    for (int j = 0; j < 8; j++) t8[j] = umin2(slot[2 * j], slot[2 * j + 1]);
    unsigned t4a = umin2(t8[0], t8[1]), t4b = umin2(t8[2], t8[3]);
    unsigned t4c = umin2(t8[4], t8[5]), t4d = umin2(t8[6], t8[7]);
    unsigned gmin = umin2(umin2(t4a, t4b), umin2(t4c, t4d));
#pragma unroll
    for (int mk = 1; mk < 16; mk <<= 1) {
      unsigned o = __shfl_xor(gmin, mk, 16);
      gmin = umin2(gmin, o);
    }
#pragma unroll
    for (int j = 0; j < NSLOT; j++)
      if (slot[j] == gmin) slot[j] = 0xFFFFFFFFu;
    if ((p & 15) == g) mycand[p >> 4] = gmin;
  }

  // ---- exact f64 rescore of my (<=2) candidates
  const int nrow = n0 + r;
  const float* rowsF = (const float*)rows4;  // rowsF[c*4+r] = x_row[c]
  unsigned long long ekey[2];
#pragma unroll
  for (int s = 0; s < 2; s++) {
    ekey[s] = ~0ull;
    if (mycand[s] != 0xFFFFFFFFu) {
      const int m = (int)(mycand[s] & 2047u);
      const float* pc = pb + m;
      double a0 = 0.0, a1 = 0.0, a2 = 0.0, a3 = 0.0;
      for (int c = 0; c < 64; c += 4) {
        a0 += (double)rowsF[(c + 0) * 4 + r] * (double)pc[(c + 0) * NPTS];
        a1 += (double)rowsF[(c + 1) * 4 + r] * (double)pc[(c + 1) * NPTS];
        a2 += (double)rowsF[(c + 2) * 4 + r] * (double)pc[(c + 2) * NPTS];
        a3 += (double)rowsF[(c + 3) * 4 + r] * (double)pc[(c + 3) * NPTS];
      }
      double d = sqd[b * NPTS + nrow] + sqd[b * NPTS + m] - 2.0 * ((a0 + a1) + (a2 + a3));
      unsigned long long ub = (unsigned long long)__double_as_longlong(d);
      ub ^= (ub >> 63) ? 0xFFFFFFFFFFFFFFFFull : 0x8000000000000000ull;
      ekey[s] = (ub & ~2047ull) | (unsigned long long)(unsigned)m;
    }
  }

  // ---- exact top-20, ascending (matches lax.top_k incl. index tie-break)
  const int row = b * NPTS + nrow;
  for (int p = 0; p < KNN; p++) {
    unsigned long long lmin = ekey[0] < ekey[1] ? ekey[0] : ekey[1];
#pragma unroll
    for (int mk = 1; mk < 16; mk <<= 1) {
      unsigned long long o = __shfl_xor(lmin, mk, 16);
      lmin = o < lmin ? o : lmin;
    }
    if (g == 0) {
      idxout[row * KNN + p] = (int)(lmin & 2047ull);
      widxS[r][p] = (int)(lmin & 2047ull);
    }
    if (ekey[0] == lmin) ekey[0] = ~0ull;
    if (ekey[1] == lmin) ekey[1] = ~0ull;
  }

  // ---- fused BN0 stats: lane = channel, accumulate over this wave's 4 rows
  __syncthreads();  // widxS visible (1-wave block: cheap)
  const int ch = lane;
  float s1 = 0.f, s2 = 0.f;
#pragma unroll
  for (int rr = 0; rr < 4; rr++) {
    const int grow = b * NPTS + n0 + rr;
    const float uo = u[grow * 64 + ch];
    for (int k = 0; k < KNN; k++) {
      int j = widxS[rr][k];  // broadcast
      float h = uo + v[(b * NPTS + j) * 64 + ch];
      s1 += h; s2 += h * h;
    }
  }
  float* sc = stats0c + (blockIdx.x & (NCOPY - 1)) * 128;
  atomicAdd(&sc[ch], s1);
  atomicAdd(&sc[64 + ch], s2);
}

// ---------------------------------------------------------------------------
// k_mid: h0n = relu(a0*(u+v)+c0); h1 = W1 @ h0n; accumulate BN1 stats;
// store per-row max/min of h1. hbuf is per-wave-private -> wave-local LDS
// fences instead of block barriers in the hot loop.
// ---------------------------------------------------------------------------
__global__ __launch_bounds__(256) void k_mid(const float* __restrict__ u,
                                             const float* __restrict__ v,
                                             const int* __restrict__ idx,
                                             const float* __restrict__ W1,
                                             const float* __restrict__ g0,
                                             const float* __restrict__ b0,
                                             const float* __restrict__ stats0c,
                                             float* __restrict__ stats1,
                                             float* __restrict__ hmax,
                                             float* __restrict__ hmin) {
  const int tid = threadIdx.x, o = tid & 63, w = tid >> 6;
  __shared__ float W1s[64][65];
  __shared__ float hbuf[4][4][64];
  for (int i = tid; i < 4096; i += 256) W1s[i >> 6][i & 63] = W1[i];
  __syncthreads();
  float ms = 0.f, qs = 0.f;
#pragma unroll
  for (int cc = 0; cc < NCOPY; cc++) {
    ms += stats0c[cc * 128 + o];
    qs += stats0c[cc * 128 + 64 + o];
  }
  float mean = ms / MTOT;
  float var  = qs / MTOT - mean * mean;
  float a0 = g0[o] * rsqrtf(var + EPS);
  float c0 = b0[o] - mean * a0;
  float w1r[64];
#pragma unroll
  for (int c = 0; c < 64; c++) w1r[c] = W1s[o][c];
  float s1 = 0.f, s2 = 0.f;
  const int r0 = blockIdx.x * 16 + w * 4;
  for (int rr = 0; rr < 4; rr++) {
    const int row = r0 + rr;
    const int b = row >> 11, n = row & 2047;
    const float uo = u[row * 64 + o];
    const int* ip = idx + row * KNN;
    float hmx = -1e30f, hmn = 1e30f;
    for (int kb = 0; kb < 5; kb++) {
#pragma unroll
      for (int kk = 0; kk < 4; kk++) {
        int j = ip[kb * 4 + kk];
        float h0 = uo + v[(b * NPTS + j) * 64 + o];
        hbuf[w][kk][o] = fmaxf(a0 * h0 + c0, 0.f);
      }
      LDS_FENCE();  // hbuf[w] is wave-private: wave-local ordering suffices
#pragma unroll
      for (int kk = 0; kk < 4; kk++) {
        float h1 = 0.f;
#pragma unroll
        for (int c4 = 0; c4 < 16; c4++) {
          float4 hh = *(const float4*)&hbuf[w][kk][c4 * 4];
          h1 += w1r[c4 * 4 + 0] * hh.x + w1r[c4 * 4 + 1] * hh.y +
                w1r[c4 * 4 + 2] * hh.z + w1r[c4 * 4 + 3] * hh.w;
        }
        s1 += h1; s2 += h1 * h1;
        hmx = fmaxf(hmx, h1); hmn = fminf(hmn, h1);
      }
      LDS_FENCE();  // reads drained before next kb overwrites hbuf[w]
    }
    hmax[(b * 64 + o) * NPTS + n] = hmx;
    hmin[(b * 64 + o) * NPTS + n] = hmn;
  }
  __shared__ float red[2][256];
  red[0][tid] = s1; red[1][tid] = s2;
  __syncthreads();
  if (tid < 64) {
    float a  = red[0][tid] + red[0][tid + 64] + red[0][tid + 128] + red[0][tid + 192];
    float bb = red[1][tid] + red[1][tid + 64] + red[1][tid + 128] + red[1][tid + 192];
    atomicAdd(&stats1[o], a);
    atomicAdd(&stats1[64 + o], bb);
  }
}

// ---------------------------------------------------------------------------
// k_final: out = relu(a1*(a1>=0 ? hmax : hmin) + c1)
// ---------------------------------------------------------------------------
__global__ __launch_bounds__(256) void k_final(const float* __restrict__ hmaxO,
                                               const float* __restrict__ hmin,
                                               const float* __restrict__ stats1,
                                               const float* __restrict__ g1,
                                               const float* __restrict__ b1,
                                               float* __restrict__ out) {
  const int i = blockIdx.x * 256 + threadIdx.x;
  const int o = (i >> 11) & 63;
  float mean = stats1[o] / MTOT;
  float var  = stats1[64 + o] / MTOT - mean * mean;
  float a1 = g1[o] * rsqrtf(var + EPS);
  float c1 = b1[o] - mean * a1;
  float pick = (a1 >= 0.f) ? hmaxO[i] : hmin[i];
  out[i] = fmaxf(a1 * pick + c1, 0.f);
}

extern "C" void kernel_launch(void* const* d_in, const int* in_sizes, int n_in,
                              void* d_out, int out_size, void* d_ws, size_t ws_size,
                              hipStream_t stream) {
  const float* pts = (const float*)d_in[0];
  const float* W0  = (const float*)d_in[1];
  const float* g0  = (const float*)d_in[2];
  const float* b0  = (const float*)d_in[3];
  const float* W1  = (const float*)d_in[4];
  const float* g1  = (const float*)d_in[5];
  const float* b1  = (const float*)d_in[6];
  float* out = (float*)d_out;
  float* ws  = (float*)d_ws;

  float*  stats0c = ws;                                    // 8 copies x 128
  float*  stats1  = ws + 1024;                             // byte 4096
  float*  u      = (float*)((char*)d_ws + WS_U_BYTE);
  float*  v      = (float*)((char*)d_ws + WS_V_BYTE);
  int*    idx    = (int*)((char*)d_ws + WS_IDX_BYTE);
  double* sqd    = (double*)((char*)d_ws + WS_SQD_BYTE);   // dead after k_knn
  float*  sq32   = (float*)((char*)d_ws + WS_SQ32_BYTE);   // dead after k_knn
  float*  hmin   = (float*)((char*)d_ws + WS_HMIN_BYTE);   // aliases sqd/sq32 (ok)
  // hmax aliases d_out (k_final rewrites it in place)

  hipMemsetAsync(d_ws, 0, 4608, stream);  // zero stats copies + stats1
  k_prep <<<256,  256, 0, stream>>>(pts, W0, sqd, sq32, u, v);
  k_knn  <<<4096,  64, 0, stream>>>(pts, sqd, sq32, u, v, idx, stats0c);
  k_mid  <<<1024, 256, 0, stream>>>(u, v, idx, W1, g0, b0, stats0c, stats1, out, hmin);
  k_final<<<4096, 256, 0, stream>>>(out, hmin, stats1, g1, b1, out);
}